// Round 2
// baseline (745.114 us; speedup 1.0000x reference)
//
#include <hip/hip_runtime.h>
#include <hip/hip_bf16.h>
#include <math.h>

#define BB 128
#define LL 4096
#define ROWB 256            // bytes per activation row (128 bf16)
#define LP3 4072            // valid rows after 3 VALID convs (4096-24)
#define TROWS 168           // LDS tile rows (128 out + 24 halo + 16 pad)
#define XB (TROWS*ROWB)     // 43008
#define WOFF XB             // weight double-buffer at 43008 (2*8192)
#define EOFF (XB + 16384)   // emb table bf16 (1024 B) at 59392
#define TOFF (EOFF + 1024)  // tokens (168*4 B) at 60416
#define WG_LAYER 147456     // weight-blob elements per layer
#define WG_LAYER_B 294912   // bytes per layer

typedef __bf16 bf16;
typedef __bf16 bf16x8 __attribute__((ext_vector_type(8)));
typedef float  f32x4  __attribute__((ext_vector_type(4)));

__device__ __forceinline__ void gload_lds16(const void* g, void* l) {
  __builtin_amdgcn_global_load_lds((const __attribute__((address_space(1))) void*)g,
                                   (__attribute__((address_space(3))) void*)l, 16, 0, 0);
}
__device__ __forceinline__ float bf2f(unsigned int u){
  union{unsigned int i; float f;} c; c.i = (u & 0xffffu) << 16; return c.f;
}
__device__ __forceinline__ unsigned short f2bfbits(float f){
  union { bf16 h; unsigned short s; } u; u.h = (bf16)f; return u.s;
}
__device__ __forceinline__ void acc8(float* a, uint4 v, float s){
  a[0] += s*bf2f(v.x); a[1] += s*bf2f(v.x>>16);
  a[2] += s*bf2f(v.y); a[3] += s*bf2f(v.y>>16);
  a[4] += s*bf2f(v.z); a[5] += s*bf2f(v.z>>16);
  a[6] += s*bf2f(v.w); a[7] += s*bf2f(v.w>>16);
}

// ---- weight re-layout: Wg[layer][tap][cb][g][cout][j], cin = cb*32+g*8+j ----
__global__ void k_prep_w(const float* __restrict__ w1, const float* __restrict__ wr,
                         bf16* __restrict__ wg){
  int idx = blockIdx.x*256 + threadIdx.x;
  if (idx >= 3*WG_LAYER) return;
  int layer = idx / WG_LAYER; int rem = idx % WG_LAYER;
  int tap = rem >> 14;
  int cb  = (rem >> 12) & 3;
  int g   = (rem >> 10) & 3;
  int cout= (rem >> 3) & 127;
  int j   = rem & 7;
  int cin = cb*32 + g*8 + j;
  float w = (layer==0) ? w1[(cout*128+cin)*9 + tap]
                       : wr[(((layer-1)*128 + cout)*128 + cin)*9 + tap];
  wg[idx] = (bf16)w;
}

// ---- fused embed + 3 conv layers; one block = one batch x 128-row tile ----
// X rows live in LDS (chunk-swizzled: byte = row*256 + ((c16 ^ (row&7))<<4)).
// Layer L output overwrites its input in place after the K-loop barrier.
__global__ __launch_bounds__(256)
void k_fused(const int* __restrict__ tokens, const float* __restrict__ emb,
             const bf16* __restrict__ wg, const float* __restrict__ b1,
             const float* __restrict__ br, bf16* __restrict__ x3){
  __shared__ __align__(16) char lds[61184];
  const int tid  = threadIdx.x;
  const int lane = tid & 63;
  const int w    = tid >> 6;
  const int wm   = w >> 1, wn = w & 1;
  const int b    = blockIdx.x >> 5;
  const int l0   = (blockIdx.x & 31) << 7;
  const int g16  = lane >> 4, r16 = lane & 15;

  const char* wbytes = (const char*)wg;
  // stage layer0 / K-step0 weights (8 KB) while we embed
  gload_lds16(wbytes + tid*16,        lds + WOFF + tid*16);
  gload_lds16(wbytes + 4096 + tid*16, lds + WOFF + 4096 + tid*16);

  int*  Tk = (int*)(lds + TOFF);
  bf16* Eb = (bf16*)(lds + EOFF);
  if (tid < TROWS){
    int l = l0 + tid; if (l > LL-1) l = LL-1;   // clamped halo (unused rows)
    Tk[tid] = tokens[b*LL + l];
  }
  Eb[tid]     = (bf16)emb[tid];
  Eb[tid+256] = (bf16)emb[tid+256];
  __syncthreads();

  // embed fill: 168 rows x 16 chunks, swizzled
  for (int t = tid; t < TROWS*16; t += 256){
    int s = t >> 4, c16 = t & 15;
    bf16x8 v = *(const bf16x8*)((const char*)Eb + Tk[s]*256 + c16*16);
    *(bf16x8*)(lds + s*ROWB + ((c16 ^ (s&7))<<4)) = v;
  }
  __syncthreads();

  const int aoff0 = g16*2048 + (wm*64 + r16)*16;

  for (int layer = 0; layer < 3; ++layer){
    const char* wl = wbytes + layer*WG_LAYER_B;
    // valid out rows: L0/L1 need 0..143, L2 needs 0..127 (wn0: 0..79, wn1: rest)
    const int nfmax = (wn == 0) ? 5 : (layer == 2 ? 3 : 4);
    f32x4 acc[4][5];
    #pragma unroll
    for (int i=0;i<4;i++)
      #pragma unroll
      for (int j=0;j<5;j++) acc[i][j] = (f32x4){0.f,0.f,0.f,0.f};

    for (int ks = 0; ks < 36; ++ks){
      if (ks < 35){                       // prefetch next K-step weights
        const char* wsn = wl + (ks+1)*8192;
        char* wd = lds + WOFF + ((ks+1)&1)*8192;
        gload_lds16(wsn + tid*16,        wd + tid*16);
        gload_lds16(wsn + 4096 + tid*16, wd + 4096 + tid*16);
      } else if (layer < 2){              // prefetch next layer step0 -> buf0
        const char* wsn = wbytes + (layer+1)*WG_LAYER_B;
        gload_lds16(wsn + tid*16,        lds + WOFF + tid*16);
        gload_lds16(wsn + 4096 + tid*16, lds + WOFF + 4096 + tid*16);
      }
      const char* wb = lds + WOFF + (ks&1)*8192;
      const int tap = ks >> 2;
      const int cbg = ((ks&3)<<2) + g16;
      bf16x8 a[4], bv[5];
      #pragma unroll
      for (int mf=0; mf<4; mf++)
        a[mf] = *(const bf16x8*)(wb + aoff0 + mf*256);
      #pragma unroll
      for (int nf=0; nf<5; nf++){
        int r = wn*80 + nf*16 + r16 + tap;       // <= 167, in bounds
        bv[nf] = *(const bf16x8*)(lds + r*ROWB + ((cbg ^ (r&7))<<4));
      }
      #pragma unroll
      for (int nf=0; nf<5; nf++)
        if (nf < nfmax)
          #pragma unroll
          for (int mf=0; mf<4; mf++)
            acc[mf][nf] = __builtin_amdgcn_mfma_f32_16x16x32_bf16(a[mf], bv[nf], acc[mf][nf], 0,0,0);
      __syncthreads();
    }

    // epilogue: +bias, pack bf16, write in place (all reads done at barrier)
    const float* bias = (layer == 0) ? b1 : (br + (layer-1)*128);
    #pragma unroll
    for (int mf=0; mf<4; mf++){
      int mb = wm*64 + mf*16 + (g16<<2);
      float4 bvx = *(const float4*)(bias + mb);
      #pragma unroll
      for (int nf=0; nf<5; nf++){
        if (nf < nfmax){
          int nn = wn*80 + nf*16 + r16;
          f32x4 v = acc[mf][nf];
          ushort4 pk;
          pk.x = f2bfbits(v[0] + bvx.x);
          pk.y = f2bfbits(v[1] + bvx.y);
          pk.z = f2bfbits(v[2] + bvx.z);
          pk.w = f2bfbits(v[3] + bvx.w);
          int chunk = (mb>>3) ^ (nn&7);
          *(ushort4*)(lds + nn*ROWB + (chunk<<4) + ((mb&7)<<1)) = pk;
        }
      }
    }
    __syncthreads();
  }

  // store rows 0..127 (swizzled image identical in LDS and global)
  char* dst = (char*)x3 + ((size_t)b*LL + l0)*ROWB;
  #pragma unroll
  for (int p=0;p<8;p++){
    int off = p*4096 + tid*16;
    int row = off >> 8;
    if (l0 + row < LP3)
      *(uint4*)(dst + off) = *(const uint4*)(lds + off);
  }
}

// ---- mean over LP3 rows ----
__global__ void k_mean(const bf16* __restrict__ x3, float* __restrict__ meanv){
  __shared__ float red[256*8];
  int b = blockIdx.x, tid = threadIdx.x;
  int lc = tid & 15, rg = tid >> 4;
  const char* base = (const char*)x3 + (size_t)b*LL*ROWB;
  float a[8] = {0,0,0,0,0,0,0,0};
  for (int l=rg; l<LP3; l+=16){
    uint4 v = *(const uint4*)(base + l*ROWB + ((lc ^ (l&7))<<4));
    acc8(a, v, 1.0f);
  }
  #pragma unroll
  for (int j=0;j<8;j++) red[tid*8+j] = a[j];
  __syncthreads();
  if (tid < 128){
    int lc2 = tid >> 3, j = tid & 7;
    float s = 0.f;
    for (int rg2=0; rg2<16; rg2++) s += red[(rg2*16+lc2)*8 + j];
    meanv[b*128 + tid] = s * (1.0f/LP3);
  }
}

// ---- q = Wq.mean + bq ; qk = Wk^T q (scaled) ; cb = q.bk (scaled) ----
__global__ void k_qk(const float* __restrict__ meanv, const float* __restrict__ wq,
                     const float* __restrict__ bq, const float* __restrict__ wk,
                     const float* __restrict__ bk, float* __restrict__ qk,
                     float* __restrict__ cbv){
  __shared__ float mv[128], qv[128];
  int b = blockIdx.x, i = threadIdx.x;
  mv[i] = meanv[b*128+i];
  __syncthreads();
  float q = bq[i];
  for (int j=0;j<128;j++) q += wq[i*128+j]*mv[j];
  qv[i] = q;
  __syncthreads();
  const float scale = 0.088388347648318447f; // 1/sqrt(128)
  float s = 0.f;
  for (int d=0; d<128; d++) s += qv[d]*wk[d*128+i];
  qk[b*128+i] = s*scale;
  if (i==0){
    float c = 0.f;
    for (int d=0; d<128; d++) c += qv[d]*bk[d];
    cbv[b] = c*scale;
  }
}

// ---- scores -> e = exp(s), per-batch sum (|s| = O(0.1): no max needed) ----
__global__ void k_scores(const bf16* __restrict__ x3, const float* __restrict__ qk,
                         const float* __restrict__ cbv, float* __restrict__ e,
                         float* __restrict__ sums){
  __shared__ float qks[128];
  __shared__ float wsum[4];
  int b = blockIdx.x >> 2, seg = blockIdx.x & 3;
  int tid = threadIdx.x, lane = tid & 63, w = tid >> 6;
  if (tid < 128) qks[tid] = qk[b*128+tid];
  __syncthreads();
  float cb = cbv[b];
  const char* base = (const char*)x3 + (size_t)b*LL*ROWB;
  int qq = lane >> 4, rr = lane & 15;
  float esum = 0.f;
  for (int it=0; it<16; it++){
    int l = seg*1024 + it*64 + w*16 + rr;
    float p = 0.f;
    #pragma unroll
    for (int i=0;i<4;i++){
      int lcn = qq*4 + i;
      uint4 v = *(const uint4*)(base + l*ROWB + ((lcn ^ (l&7))<<4));
      const float* qp = qks + lcn*8;
      p += bf2f(v.x)*qp[0] + bf2f(v.x>>16)*qp[1]
         + bf2f(v.y)*qp[2] + bf2f(v.y>>16)*qp[3]
         + bf2f(v.z)*qp[4] + bf2f(v.z>>16)*qp[5]
         + bf2f(v.w)*qp[6] + bf2f(v.w>>16)*qp[7];
    }
    p += __shfl_xor(p, 16);
    p += __shfl_xor(p, 32);
    float ev = __expf(p + cb);
    if (l < LP3){
      if (qq == 0) e[b*LL + l] = ev;
      esum += 0.25f * ev;
    }
  }
  for (int d=1; d<64; d<<=1) esum += __shfl_xor(esum, d);
  if (lane==0) wsum[w] = esum;
  __syncthreads();
  if (tid==0) atomicAdd(&sums[b], wsum[0]+wsum[1]+wsum[2]+wsum[3]);
}

// ---- xa[c] = sum_l e[l]*x[l][c] (unnormalized) ----
__global__ void k_wsum(const bf16* __restrict__ x3, const float* __restrict__ e,
                       float* __restrict__ xa){
  __shared__ float red[256*8];
  int b = blockIdx.x, tid = threadIdx.x;
  int lc = tid & 15, rg = tid >> 4;
  const char* base = (const char*)x3 + (size_t)b*LL*ROWB;
  float a[8] = {0,0,0,0,0,0,0,0};
  for (int l=rg; l<LP3; l+=16){
    float wv = e[b*LL + l];
    uint4 v = *(const uint4*)(base + l*ROWB + ((lc ^ (l&7))<<4));
    acc8(a, v, wv);
  }
  #pragma unroll
  for (int j=0;j<8;j++) red[tid*8+j] = a[j];
  __syncthreads();
  if (tid < 128){
    int lc2 = tid >> 3, j = tid & 7;
    float s = 0.f;
    for (int rg2=0; rg2<16; rg2++) s += red[(rg2*16+lc2)*8 + j];
    xa[b*128 + tid] = s;
  }
}

// ---- out = Wv.(xa/sum) + bv ----
__global__ void k_out(const float* __restrict__ xa, const float* __restrict__ sums,
                      const float* __restrict__ wv, const float* __restrict__ bv,
                      float* __restrict__ out){
  __shared__ float xs[128];
  int b = blockIdx.x, i = threadIdx.x;
  xs[i] = xa[b*128+i] / sums[b];
  __syncthreads();
  float o = bv[i];
  for (int j=0;j<128;j++) o += wv[i*128+j]*xs[j];
  out[b*128+i] = o;
}

extern "C" void kernel_launch(void* const* d_in, const int* in_sizes, int n_in,
                              void* d_out, int out_size, void* d_ws, size_t ws_size,
                              hipStream_t stream){
  const int*   tokens = (const int*)d_in[0];
  const float* emb    = (const float*)d_in[1];
  const float* w1     = (const float*)d_in[2];
  const float* b1     = (const float*)d_in[3];
  const float* wr     = (const float*)d_in[4];
  const float* br     = (const float*)d_in[5];
  const float* wqw    = (const float*)d_in[6];
  const float* wqb    = (const float*)d_in[7];
  const float* wkw    = (const float*)d_in[8];
  const float* wkb    = (const float*)d_in[9];
  const float* wvw    = (const float*)d_in[10];
  const float* wvb    = (const float*)d_in[11];
  float* out = (float*)d_out;

  // workspace layout (all 16B-aligned)
  const size_t X3SZ = (size_t)BB*LL*ROWB;            // 134217728
  const size_t NEED = X3SZ + (size_t)WG_LAYER_B*3 + 2097152 + 65536*3 + 8192;
  if (ws_size < NEED){                               // graceful failure, no OOB
    hipMemsetAsync(d_out, 0, (size_t)out_size*4, stream);
    return;
  }
  char* ws = (char*)d_ws;
  bf16*  x3    = (bf16*)ws;
  bf16*  wg    = (bf16*)(ws + X3SZ);
  char*  aux   = ws + X3SZ + WG_LAYER_B*3;
  float* ebuf  = (float*)aux;                        // 2 MB
  float* meanv = (float*)(aux + 2097152);
  float* qkbuf = (float*)(aux + 2097152 + 65536);
  float* cbbuf = (float*)(aux + 2097152 + 131072);
  float* sums  = (float*)(aux + 2097152 + 131072 + 4096);
  float* xabuf = (float*)(aux + 2097152 + 131072 + 8192);

  hipMemsetAsync(sums, 0, 512, stream);
  k_prep_w<<<1728, 256, 0, stream>>>(w1, wr, wg);
  k_fused<<<4096, 256, 0, stream>>>(tokens, emb, wg, b1, br, x3);
  k_mean<<<128, 256, 0, stream>>>(x3, meanv);
  k_qk<<<128, 128, 0, stream>>>(meanv, wqw, wqb, wkw, wkb, qkbuf, cbbuf);
  k_scores<<<512, 256, 0, stream>>>(x3, qkbuf, cbbuf, ebuf, sums);
  k_wsum<<<128, 256, 0, stream>>>(x3, ebuf, xabuf);
  k_out<<<128, 128, 0, stream>>>(xabuf, sums, wvw, wvb, out);
}

// Round 3
// 570.383 us; speedup vs baseline: 1.3063x; 1.3063x over previous
//
#include <hip/hip_runtime.h>
#include <hip/hip_bf16.h>
#include <math.h>

#define BB 128
#define LL 4096
#define ROWB 256            // bytes per activation row (128 bf16)
#define LP3 4072            // valid rows after 3 VALID convs
#define TROWS 168           // LDS tile rows (128 out + 24 halo + clamp pad)
#define XB (TROWS*ROWB)     // 43008
#define WOFF XB             // 4-slot weight ring at 43008
#define RING 32768          // 4 x 8192
#define EOFF (WOFF + RING)  // emb table bf16 (1024 B) at 75776
#define TOFF (EOFF + 1024)  // tokens (168*4 B) at 76800
#define LDSSZ (TOFF + 672)  // 77472
#define NSTEP 108           // 3 layers x 36 K-steps
#define WELEM (NSTEP*4096)  // 442368 real weight elements

typedef __bf16 bf16;
typedef __bf16 bf16x8 __attribute__((ext_vector_type(8)));
typedef float  f32x4  __attribute__((ext_vector_type(4)));

#define MFMA(va,vb,vc) __builtin_amdgcn_mfma_f32_16x16x32_bf16(va,vb,vc,0,0,0)

__device__ __forceinline__ void gload_lds16(const void* g, void* l) {
  __builtin_amdgcn_global_load_lds((const __attribute__((address_space(1))) void*)g,
                                   (__attribute__((address_space(3))) void*)l, 16, 0, 0);
}
__device__ __forceinline__ float bf2f(unsigned int u){
  union{unsigned int i; float f;} c; c.i = (u & 0xffffu) << 16; return c.f;
}
__device__ __forceinline__ unsigned short f2bfbits(float f){
  union { bf16 h; unsigned short s; } u; u.h = (bf16)f; return u.s;
}
__device__ __forceinline__ void acc8(float* a, uint4 v, float s){
  a[0] += s*bf2f(v.x); a[1] += s*bf2f(v.x>>16);
  a[2] += s*bf2f(v.y); a[3] += s*bf2f(v.y>>16);
  a[4] += s*bf2f(v.z); a[5] += s*bf2f(v.z>>16);
  a[6] += s*bf2f(v.w); a[7] += s*bf2f(v.w>>16);
}

// ---- weight re-layout. Step s = layer*36 + tap*4 + cb (8 KB each).
// Within step: elem = wm*2048 + mf*512 + g*128 + c16*8 + j
//   cout = wm*64 + mf*16 + c16 ; cin = cb*32 + g*8 + j
// -> wave A-read for (wm,mf) is 1024 CONTIGUOUS bytes (lane*16): conflict-free.
__global__ void k_prep_w(const float* __restrict__ w1, const float* __restrict__ wr,
                         bf16* __restrict__ wg){
  int idx = blockIdx.x*256 + threadIdx.x;
  if (idx >= WELEM) return;
  int s    = idx >> 12;
  int r12  = idx & 4095;
  int wm   = r12 >> 11;
  int mf   = (r12 >> 9) & 3;
  int g    = (r12 >> 7) & 3;
  int c16  = (r12 >> 3) & 15;
  int j    = r12 & 7;
  int layer = s / 36;
  int w36   = s - layer*36;
  int tap = w36 >> 2, cb = w36 & 3;
  int cout = wm*64 + mf*16 + c16;
  int cin  = cb*32 + g*8 + j;
  float w = (layer==0) ? w1[(cout*128+cin)*9 + tap]
                       : wr[(((layer-1)*128 + cout)*128 + cin)*9 + tap];
  wg[idx] = (bf16)w;
}

// ---- fused embed + 3 convs + mean partials. Counted-vmcnt weight pipeline. ----
__global__ __launch_bounds__(256)
void k_fused(const int* __restrict__ tokens, const float* __restrict__ emb,
             const bf16* __restrict__ wg, const float* __restrict__ b1,
             const float* __restrict__ br, bf16* __restrict__ x3,
             float* __restrict__ meanv){
  __shared__ __align__(16) char lds[LDSSZ];
  const int tid  = threadIdx.x;
  const int lane = tid & 63;
  const int w    = tid >> 6;
  const int wm   = w >> 1, wn = w & 1;
  const int b    = blockIdx.x >> 5;
  const int l0   = (blockIdx.x & 31) << 7;
  const int g16  = lane >> 4, r16 = lane & 15;
  const char* wbytes = (const char*)wg;

  // prologue: issue weight steps 0..2 into ring slots 0..2 (6 loads in flight)
  #pragma unroll
  for (int s=0;s<3;s++){
    gload_lds16(wbytes + s*8192 + tid*16,        lds + WOFF + s*8192 + tid*16);
    gload_lds16(wbytes + s*8192 + 4096 + tid*16, lds + WOFF + s*8192 + 4096 + tid*16);
  }
  int*  Tk = (int*)(lds + TOFF);
  bf16* Eb = (bf16*)(lds + EOFF);
  if (tid < TROWS){
    int l = l0 + tid; if (l > LL-1) l = LL-1;   // clamped halo (rows masked later)
    Tk[tid] = tokens[b*LL + l];
  }
  Eb[tid]     = (bf16)emb[tid];
  Eb[tid+256] = (bf16)emb[tid+256];
  asm volatile("s_waitcnt lgkmcnt(0)" ::: "memory");
  __builtin_amdgcn_s_barrier();
  // embed fill: 168 rows x 16 chunks, chunk-XOR-swizzled
  for (int t2 = tid; t2 < TROWS*16; t2 += 256){
    int s = t2 >> 4, c16 = t2 & 15;
    bf16x8 v = *(const bf16x8*)((const char*)Eb + Tk[s]*256 + c16*16);
    *(bf16x8*)(lds + s*ROWB + ((c16 ^ (s&7))<<4)) = v;
  }
  asm volatile("s_waitcnt lgkmcnt(0)" ::: "memory");
  __builtin_amdgcn_s_barrier();

  for (int layer = 0; layer < 3; ++layer){
    const int rowbase = wn * ((layer==2) ? 64 : 80);
    const bool five = (layer < 2) && (wn == 0);
    f32x4 acc[4][5];
    #pragma unroll
    for (int i=0;i<4;i++)
      #pragma unroll
      for (int j=0;j<5;j++) acc[i][j] = (f32x4){0.f,0.f,0.f,0.f};

    for (int ks = 0; ks < 36; ++ks){
      const int t = layer*36 + ks;
      // issue step t+3 into slot (t+3)&3 (blob padded: always valid to read)
      {
        const char* wsn = wbytes + (size_t)(t+3)*8192;
        char* wd = lds + WOFF + (((t+3)&3)<<13);
        gload_lds16(wsn + tid*16,        wd + tid*16);
        gload_lds16(wsn + 4096 + tid*16, wd + 4096 + tid*16);
      }
      // A fragments: contiguous 1024 B per (wm,mf)
      const char* wb = lds + WOFF + ((t&3)<<13) + wm*4096 + (lane<<4);
      bf16x8 a0 = *(const bf16x8*)(wb);
      bf16x8 a1 = *(const bf16x8*)(wb + 1024);
      bf16x8 a2 = *(const bf16x8*)(wb + 2048);
      bf16x8 a3 = *(const bf16x8*)(wb + 3072);
      // B fragments from swizzled X rows
      const int tap = ks >> 2;
      const int cbg = ((ks&3)<<2) + g16;
      bf16x8 bv[4]; bf16x8 b4;
      #pragma unroll
      for (int nf=0; nf<4; nf++){
        int r = rowbase + nf*16 + r16 + tap;
        bv[nf] = *(const bf16x8*)(lds + r*ROWB + ((cbg ^ (r&7))<<4));
      }
      if (five){
        int r = rowbase + 64 + r16 + tap;
        b4 = *(const bf16x8*)(lds + r*ROWB + ((cbg ^ (r&7))<<4));
      }
      // counted wait: step t+1's loads landed (4 = 2 ops x {t+2,t+3})
      asm volatile("s_waitcnt vmcnt(4)" ::: "memory");
      __builtin_amdgcn_s_setprio(1);
      #pragma unroll
      for (int nf=0; nf<4; nf++){
        acc[0][nf] = MFMA(a0, bv[nf], acc[0][nf]);
        acc[1][nf] = MFMA(a1, bv[nf], acc[1][nf]);
        acc[2][nf] = MFMA(a2, bv[nf], acc[2][nf]);
        acc[3][nf] = MFMA(a3, bv[nf], acc[3][nf]);
      }
      if (five){
        acc[0][4] = MFMA(a0, b4, acc[0][4]);
        acc[1][4] = MFMA(a1, b4, acc[1][4]);
        acc[2][4] = MFMA(a2, b4, acc[2][4]);
        acc[3][4] = MFMA(a3, b4, acc[3][4]);
      }
      __builtin_amdgcn_s_setprio(0);
      __builtin_amdgcn_s_barrier();
    }

    // epilogue: +bias, pack bf16, write in place (reads done at last barrier)
    const float* bias = (layer == 0) ? b1 : (br + (layer-1)*128);
    const int nfmax = five ? 5 : 4;
    #pragma unroll
    for (int mf=0; mf<4; mf++){
      int mb = wm*64 + mf*16 + (g16<<2);
      float4 bvx = *(const float4*)(bias + mb);
      #pragma unroll
      for (int nf=0; nf<5; nf++){
        if (nf < nfmax){
          int nn = rowbase + nf*16 + r16;
          f32x4 v = acc[mf][nf];
          ushort4 pk;
          pk.x = f2bfbits(v[0] + bvx.x);
          pk.y = f2bfbits(v[1] + bvx.y);
          pk.z = f2bfbits(v[2] + bvx.z);
          pk.w = f2bfbits(v[3] + bvx.w);
          int chunk = (mb>>3) ^ (nn&7);
          *(ushort4*)(lds + nn*ROWB + (chunk<<4) + ((mb&7)<<1)) = pk;
        }
      }
    }
    asm volatile("s_waitcnt lgkmcnt(0)" ::: "memory");
    __builtin_amdgcn_s_barrier();
  }

  // store rows 0..127 (swizzled image identical in LDS and global)
  char* dst = (char*)x3 + ((size_t)b*LL + l0)*ROWB;
  #pragma unroll
  for (int p=0;p<8;p++){
    int off = p*4096 + tid*16;
    int row = off >> 8;
    if (l0 + row < LP3)
      *(uint4*)(dst + off) = *(const uint4*)(lds + off);
  }
  // mean partials: column sums of this tile -> atomicAdd (meanv pre-zeroed)
  {
    int lc = tid & 15, rg = tid >> 4;
    float am[8] = {0,0,0,0,0,0,0,0};
    for (int l = rg; l < 128; l += 16){
      if (l0 + l < LP3){
        uint4 v = *(const uint4*)(lds + l*ROWB + ((lc ^ (l&7))<<4));
        acc8(am, v, 1.0f);
      }
    }
    float* red = (float*)(lds + WOFF + 24576);   // ring slot 3 (dead; pads hit 0..2)
    #pragma unroll
    for (int j=0;j<8;j++) red[tid*8+j] = am[j];
    __syncthreads();
    if (tid < 128){
      int lc2 = tid >> 3, j = tid & 7;
      float s = 0.f;
      for (int rg2=0; rg2<16; rg2++) s += red[(rg2*16+lc2)*8 + j];
      atomicAdd(&meanv[b*128 + tid], s);
    }
  }
}

// ---- q = Wq.(mean) + bq ; qk = Wk^T q (scaled) ; cb = q.bk (scaled) ----
__global__ void k_qk(const float* __restrict__ meanv, const float* __restrict__ wq,
                     const float* __restrict__ bq, const float* __restrict__ wk,
                     const float* __restrict__ bk, float* __restrict__ qk,
                     float* __restrict__ cbv){
  __shared__ float mv[128], qv[128];
  int b = blockIdx.x, i = threadIdx.x;
  mv[i] = meanv[b*128+i] * (1.0f/LP3);
  __syncthreads();
  float q = bq[i];
  for (int j=0;j<128;j++) q += wq[i*128+j]*mv[j];
  qv[i] = q;
  __syncthreads();
  const float scale = 0.088388347648318447f; // 1/sqrt(128)
  float s = 0.f;
  for (int d=0; d<128; d++) s += qv[d]*wk[d*128+i];
  qk[b*128+i] = s*scale;
  if (i==0){
    float c = 0.f;
    for (int d=0; d<128; d++) c += qv[d]*bk[d];
    cbv[b] = c*scale;
  }
}

// ---- fused scores + weighted sum: one pass over x3.
// e = exp(x.qk + cb) (|score| = O(0.1): no max subtraction needed);
// accumulate sum(e) and sum(e*x[c]) via atomics (xa/sums pre-zeroed).
__global__ __launch_bounds__(256)
void k_attn(const bf16* __restrict__ x3, const float* __restrict__ qk,
            const float* __restrict__ cbv, float* __restrict__ xa,
            float* __restrict__ sums){
  __shared__ float qks[128];
  __shared__ float red[2048];
  __shared__ float wsm[4];
  int b = blockIdx.x >> 2, seg = blockIdx.x & 3;
  int tid = threadIdx.x;
  int lc = tid & 15, rg = tid >> 4;
  if (tid < 128) qks[tid] = qk[b*128 + tid];
  __syncthreads();
  float cb = cbv[b];
  const char* base = (const char*)x3 + (size_t)b*LL*ROWB;
  const float* qp = qks + lc*8;
  float a[8] = {0,0,0,0,0,0,0,0};
  float esum = 0.f;
  for (int it=0; it<64; it++){
    int l = seg*1024 + it*16 + rg;
    uint4 v = *(const uint4*)(base + l*ROWB + ((lc ^ (l&7))<<4));
    float p = bf2f(v.x)*qp[0] + bf2f(v.x>>16)*qp[1]
            + bf2f(v.y)*qp[2] + bf2f(v.y>>16)*qp[3]
            + bf2f(v.z)*qp[4] + bf2f(v.z>>16)*qp[5]
            + bf2f(v.w)*qp[6] + bf2f(v.w>>16)*qp[7];
    p += __shfl_xor(p, 1); p += __shfl_xor(p, 2);
    p += __shfl_xor(p, 4); p += __shfl_xor(p, 8);
    if (l < LP3){
      float e = __expf(p + cb);
      esum += e;
      acc8(a, v, e);
    }
  }
  #pragma unroll
  for (int j=0;j<8;j++) red[tid*8+j] = a[j];
  esum += __shfl_xor(esum, 16);      // group-uniform -> sum the 4 groups
  esum += __shfl_xor(esum, 32);
  if ((tid & 63) == 0) wsm[tid>>6] = esum;
  __syncthreads();
  if (tid < 128){
    int lc2 = tid >> 3, j = tid & 7;
    float s = 0.f;
    for (int rg2=0; rg2<16; rg2++) s += red[(rg2*16+lc2)*8 + j];
    atomicAdd(&xa[b*128 + tid], s);
  }
  if (tid == 0) atomicAdd(&sums[b], wsm[0]+wsm[1]+wsm[2]+wsm[3]);
}

// ---- out = Wv.(xa/sum) + bv ----
__global__ void k_out(const float* __restrict__ xa, const float* __restrict__ sums,
                      const float* __restrict__ wv, const float* __restrict__ bv,
                      float* __restrict__ out){
  __shared__ float xs[128];
  int b = blockIdx.x, i = threadIdx.x;
  xs[i] = xa[b*128+i] / sums[b];
  __syncthreads();
  float o = bv[i];
  for (int j=0;j<128;j++) o += wv[i*128+j]*xs[j];
  out[b*128+i] = o;
}

extern "C" void kernel_launch(void* const* d_in, const int* in_sizes, int n_in,
                              void* d_out, int out_size, void* d_ws, size_t ws_size,
                              hipStream_t stream){
  const int*   tokens = (const int*)d_in[0];
  const float* emb    = (const float*)d_in[1];
  const float* w1     = (const float*)d_in[2];
  const float* b1     = (const float*)d_in[3];
  const float* wr     = (const float*)d_in[4];
  const float* br     = (const float*)d_in[5];
  const float* wqw    = (const float*)d_in[6];
  const float* wqb    = (const float*)d_in[7];
  const float* wkw    = (const float*)d_in[8];
  const float* wkb    = (const float*)d_in[9];
  const float* wvw    = (const float*)d_in[10];
  const float* wvb    = (const float*)d_in[11];
  float* out = (float*)d_out;

  const size_t X3SZ  = (size_t)BB*LL*ROWB;           // 134217728
  const size_t WGSZ  = (size_t)(NSTEP+3)*8192;       // 909312 (3 pad steps)
  const size_t AUXSZ = 204800;
  const size_t NEED  = X3SZ + WGSZ + AUXSZ;          // ~135.3 MB
  if (ws_size < NEED){
    hipMemsetAsync(d_out, 0, (size_t)out_size*4, stream);
    return;
  }
  char* ws = (char*)d_ws;
  bf16*  x3    = (bf16*)ws;
  bf16*  wg    = (bf16*)(ws + X3SZ);
  char*  aux   = ws + X3SZ + WGSZ;
  float* meanv = (float*)aux;                        // 65536
  float* xabuf = (float*)(aux + 65536);              // 65536
  float* sums  = (float*)(aux + 131072);             // 4096
  float* qkbuf = (float*)(aux + 135168);             // 65536
  float* cbbuf = (float*)(aux + 200704);             // 4096

  hipMemsetAsync(aux, 0, 135168, stream);            // meanv + xa + sums
  k_prep_w<<<1728, 256, 0, stream>>>(w1, wr, wg);
  k_fused<<<4096, 256, 0, stream>>>(tokens, emb, wg, b1, br, x3, meanv);
  k_qk<<<128, 128, 0, stream>>>(meanv, wqw, wqb, wkw, wkb, qkbuf, cbbuf);
  k_attn<<<512, 256, 0, stream>>>(x3, qkbuf, cbbuf, xabuf, sums);
  k_out<<<128, 128, 0, stream>>>(xabuf, sums, wvw, wvb, out);
}

// Round 4
// 528.890 us; speedup vs baseline: 1.4088x; 1.0785x over previous
//
#include <hip/hip_runtime.h>
#include <hip/hip_bf16.h>
#include <math.h>

#define BB 128
#define LL 4096
#define ROWB 256            // bytes per activation row (128 bf16)
#define LP3 4072            // valid rows after 3 VALID convs
#define TROWS 168           // LDS tile rows (128 out + 24 halo + clamp pad)
#define XB (TROWS*ROWB)     // 43008
#define WOFF XB             // 4-slot weight ring at 43008
#define RING 32768          // 4 x 8192
#define EOFF (WOFF + RING)  // emb table bf16 (1024 B)
#define TOFF (EOFF + 1024)  // tokens (168*4 B)
#define LDSSZ (TOFF + 672)  // 77472
#define NSTEP 108           // 3 layers x 36 K-steps
#define WELEM (NSTEP*4096)  // real weight elements

typedef __bf16 bf16;
typedef __bf16 bf16x8 __attribute__((ext_vector_type(8)));
typedef float  f32x4  __attribute__((ext_vector_type(4)));

#define MFMA(va,vb,vc) __builtin_amdgcn_mfma_f32_16x16x32_bf16(va,vb,vc,0,0,0)

__device__ __forceinline__ void gload_lds16(const void* g, void* l) {
  __builtin_amdgcn_global_load_lds((const __attribute__((address_space(1))) void*)g,
                                   (__attribute__((address_space(3))) void*)l, 16, 0, 0);
}
__device__ __forceinline__ float bf2f(unsigned int u){
  union{unsigned int i; float f;} c; c.i = (u & 0xffffu) << 16; return c.f;
}
__device__ __forceinline__ unsigned short f2bfbits(float f){
  union { bf16 h; unsigned short s; } u; u.h = (bf16)f; return u.s;
}
__device__ __forceinline__ void acc8(float* a, uint4 v, float s){
  a[0] += s*bf2f(v.x); a[1] += s*bf2f(v.x>>16);
  a[2] += s*bf2f(v.y); a[3] += s*bf2f(v.y>>16);
  a[4] += s*bf2f(v.z); a[5] += s*bf2f(v.z>>16);
  a[6] += s*bf2f(v.w); a[7] += s*bf2f(v.w>>16);
}

// ---- weight re-layout. Step s = layer*36 + tap*4 + cb (8 KB each).
// elem = wm*2048 + mf*512 + g*128 + c16*8 + j ; cout = wm*64+mf*16+c16 ; cin = cb*32+g*8+j
__global__ void k_prep_w(const float* __restrict__ w1, const float* __restrict__ wr,
                         bf16* __restrict__ wg){
  int idx = blockIdx.x*256 + threadIdx.x;
  if (idx >= WELEM) return;
  int s    = idx >> 12;
  int r12  = idx & 4095;
  int wm   = r12 >> 11;
  int mf   = (r12 >> 9) & 3;
  int g    = (r12 >> 7) & 3;
  int c16  = (r12 >> 3) & 15;
  int j    = r12 & 7;
  int layer = s / 36;
  int w36   = s - layer*36;
  int tap = w36 >> 2, cb = w36 & 3;
  int cout = wm*64 + mf*16 + c16;
  int cin  = cb*32 + g*8 + j;
  float w = (layer==0) ? w1[(cout*128+cin)*9 + tap]
                       : wr[(((layer-1)*128 + cout)*128 + cin)*9 + tap];
  wg[idx] = (bf16)w;
}

#define VMCNT4 asm volatile("s_waitcnt vmcnt(4)" ::: "memory")
#define LGKM0  asm volatile("s_waitcnt lgkmcnt(0)" ::: "memory")

#define ISSUE_W(tt) do{                                                  \
  const char* wsn_ = wbytes + (size_t)(tt)*8192 + tid*16;                \
  char* wd_ = lds + WOFF + (((tt)&3)<<13) + tid*16;                      \
  gload_lds16(wsn_,        wd_);                                         \
  gload_lds16(wsn_ + 4096, wd_ + 4096);                                  \
}while(0)

// fragment preload for K-step kss (A from ring slot, B from swizzled X rows)
#define PRELOAD(A0,A1,A2,A3,B0,B1,B2,B3,B4,kss) do{                      \
  const char* wbp_ = wABase + (((layer36+(kss))&3)<<13);                 \
  A0 = *(const bf16x8*)(wbp_);                                           \
  A1 = *(const bf16x8*)(wbp_+1024);                                      \
  A2 = *(const bf16x8*)(wbp_+2048);                                      \
  A3 = *(const bf16x8*)(wbp_+3072);                                      \
  const int tap_ = (kss)>>2;                                             \
  const int ch_ = ((((((kss)&3)<<2)+g16) ^ ((r16+tap_)&7)) << 4);        \
  const char* bp_ = bBase + tap_*256 + ch_;                              \
  B0 = *(const bf16x8*)(bp_);                                            \
  B1 = *(const bf16x8*)(bp_+4096);                                       \
  B2 = *(const bf16x8*)(bp_+8192);                                       \
  B3 = *(const bf16x8*)(bp_+12288);                                      \
  if (five) B4 = *(const bf16x8*)(bp_+16384);                            \
}while(0)

#define DOMFMA(A0,A1,A2,A3,B0,B1,B2,B3,B4) do{                           \
  __builtin_amdgcn_s_setprio(1);                                         \
  acc[0][0]=MFMA(A0,B0,acc[0][0]); acc[1][0]=MFMA(A1,B0,acc[1][0]);      \
  acc[2][0]=MFMA(A2,B0,acc[2][0]); acc[3][0]=MFMA(A3,B0,acc[3][0]);      \
  acc[0][1]=MFMA(A0,B1,acc[0][1]); acc[1][1]=MFMA(A1,B1,acc[1][1]);      \
  acc[2][1]=MFMA(A2,B1,acc[2][1]); acc[3][1]=MFMA(A3,B1,acc[3][1]);      \
  acc[0][2]=MFMA(A0,B2,acc[0][2]); acc[1][2]=MFMA(A1,B2,acc[1][2]);      \
  acc[2][2]=MFMA(A2,B2,acc[2][2]); acc[3][2]=MFMA(A3,B2,acc[3][2]);      \
  acc[0][3]=MFMA(A0,B3,acc[0][3]); acc[1][3]=MFMA(A1,B3,acc[1][3]);      \
  acc[2][3]=MFMA(A2,B3,acc[2][3]); acc[3][3]=MFMA(A3,B3,acc[3][3]);      \
  if (five){                                                             \
    acc[0][4]=MFMA(A0,B4,acc[0][4]); acc[1][4]=MFMA(A1,B4,acc[1][4]);    \
    acc[2][4]=MFMA(A2,B4,acc[2][4]); acc[3][4]=MFMA(A3,B4,acc[3][4]);    \
  }                                                                      \
  __builtin_amdgcn_s_setprio(0);                                         \
}while(0)

// ---- fused embed + 3 convs + mean partials; double-buffered frag pipeline ----
__global__ __launch_bounds__(256, 2)
void k_fused(const int* __restrict__ tokens, const float* __restrict__ emb,
             const bf16* __restrict__ wg, const float* __restrict__ b1,
             const float* __restrict__ br, bf16* __restrict__ x3,
             float* __restrict__ meanv){
  __shared__ __align__(16) char lds[LDSSZ];
  const int tid  = threadIdx.x;
  const int lane = tid & 63;
  const int w    = tid >> 6;
  const int wm   = w >> 1, wn = w & 1;
  const int b    = blockIdx.x >> 5;
  const int l0   = (blockIdx.x & 31) << 7;
  const int g16  = lane >> 4, r16 = lane & 15;
  const char* wbytes = (const char*)wg;

  // prologue: issue weight steps 0..2 into ring slots 0..2 (6 loads in flight)
  #pragma unroll
  for (int s=0;s<3;s++){
    gload_lds16(wbytes + s*8192 + tid*16,        lds + WOFF + s*8192 + tid*16);
    gload_lds16(wbytes + s*8192 + 4096 + tid*16, lds + WOFF + s*8192 + 4096 + tid*16);
  }
  int*  Tk = (int*)(lds + TOFF);
  bf16* Eb = (bf16*)(lds + EOFF);
  if (tid < TROWS){
    int l = l0 + tid; if (l > LL-1) l = LL-1;   // clamped halo (rows masked later)
    Tk[tid] = tokens[b*LL + l];
  }
  Eb[tid]     = (bf16)emb[tid];
  Eb[tid+256] = (bf16)emb[tid+256];
  LGKM0;
  __builtin_amdgcn_s_barrier();
  for (int t2 = tid; t2 < TROWS*16; t2 += 256){
    int s = t2 >> 4, c16 = t2 & 15;
    bf16x8 v = *(const bf16x8*)((const char*)Eb + Tk[s]*256 + c16*16);
    *(bf16x8*)(lds + s*ROWB + ((c16 ^ (s&7))<<4)) = v;
  }
  LGKM0;
  __builtin_amdgcn_s_barrier();

  const char* wABase = lds + WOFF + (wm<<12) + (lane<<4);

  for (int layer = 0; layer < 3; ++layer){
    const int layer36 = layer*36;
    const int rowbase = wn * ((layer==2) ? 64 : 80);
    const bool five = (layer < 2) && (wn == 0);
    const char* bBase = lds + (rowbase + r16)*256;
    f32x4 acc[4][5];
    #pragma unroll
    for (int i=0;i<4;i++)
      #pragma unroll
      for (int j=0;j<5;j++) acc[i][j] = (f32x4){0.f,0.f,0.f,0.f};

    bf16x8 A0,A1,A2,A3,B0,B1,B2,B3,B4;
    bf16x8 C0,C1,C2,C3,D0,D1,D2,D3,D4;
    VMCNT4;                          // step layer36+1 (and older) landed
    PRELOAD(A0,A1,A2,A3,B0,B1,B2,B3,B4, 0);

    #pragma unroll 1
    for (int it = 0; it < 18; ++it){
      const int ks = it << 1;
      const int t  = layer36 + ks;
      ISSUE_W(t+3);
      VMCNT4;                        // t+1's weights landed
      PRELOAD(C0,C1,C2,C3,D0,D1,D2,D3,D4, ks+1);
      DOMFMA(A0,A1,A2,A3,B0,B1,B2,B3,B4);
      __builtin_amdgcn_s_barrier();
      ISSUE_W(t+4);
      VMCNT4;                        // t+2's weights landed
      if (ks < 34) PRELOAD(A0,A1,A2,A3,B0,B1,B2,B3,B4, ks+2);
      DOMFMA(C0,C1,C2,C3,D0,D1,D2,D3,D4);
      __builtin_amdgcn_s_barrier();
    }

    // epilogue: +bias, pack bf16, write in place (all reads done at barrier)
    const float* bias = (layer == 0) ? b1 : (br + (layer-1)*128);
    const int nfmax = five ? 5 : 4;
    #pragma unroll
    for (int mf=0; mf<4; mf++){
      int mb = wm*64 + mf*16 + (g16<<2);
      float4 bvx = *(const float4*)(bias + mb);
      #pragma unroll
      for (int nf=0; nf<5; nf++){
        if (nf < nfmax){
          int nn = rowbase + nf*16 + r16;
          f32x4 v = acc[mf][nf];
          ushort4 pk;
          pk.x = f2bfbits(v[0] + bvx.x);
          pk.y = f2bfbits(v[1] + bvx.y);
          pk.z = f2bfbits(v[2] + bvx.z);
          pk.w = f2bfbits(v[3] + bvx.w);
          int chunk = (mb>>3) ^ (nn&7);
          *(ushort4*)(lds + nn*ROWB + (chunk<<4) + ((mb&7)<<1)) = pk;
        }
      }
    }
    LGKM0;
    __builtin_amdgcn_s_barrier();
  }

  // store rows 0..127 (swizzled image identical in LDS and global)
  char* dst = (char*)x3 + ((size_t)b*LL + l0)*ROWB;
  #pragma unroll
  for (int p=0;p<8;p++){
    int off = p*4096 + tid*16;
    int row = off >> 8;
    if (l0 + row < LP3)
      *(uint4*)(dst + off) = *(const uint4*)(lds + off);
  }
  // mean partials: column sums of this tile -> atomicAdd (meanv pre-zeroed)
  {
    int lc = tid & 15, rg = tid >> 4;
    float am[8] = {0,0,0,0,0,0,0,0};
    for (int l = rg; l < 128; l += 16){
      if (l0 + l < LP3){
        uint4 v = *(const uint4*)(lds + l*ROWB + ((lc ^ (l&7))<<4));
        acc8(am, v, 1.0f);
      }
    }
    float* red = (float*)(lds + WOFF + 24576);   // ring slot 3 (dead now)
    __syncthreads();
    #pragma unroll
    for (int j=0;j<8;j++) red[tid*8+j] = am[j];
    __syncthreads();
    if (tid < 128){
      int lc2 = tid >> 3, j = tid & 7;
      float s = 0.f;
      for (int rg2=0; rg2<16; rg2++) s += red[(rg2*16+lc2)*8 + j];
      atomicAdd(&meanv[b*128 + tid], s);
    }
  }
}

// ---- q = Wq.(mean) + bq ; qk = Wk^T q (scaled) ; cb = q.bk (scaled) ----
__global__ void k_qk(const float* __restrict__ meanv, const float* __restrict__ wq,
                     const float* __restrict__ bq, const float* __restrict__ wk,
                     const float* __restrict__ bk, float* __restrict__ qk,
                     float* __restrict__ cbv){
  __shared__ float mv[128], qv[128];
  int b = blockIdx.x, i = threadIdx.x;
  mv[i] = meanv[b*128+i] * (1.0f/LP3);
  __syncthreads();
  float q = bq[i];
  for (int j=0;j<128;j++) q += wq[i*128+j]*mv[j];
  qv[i] = q;
  __syncthreads();
  const float scale = 0.088388347648318447f; // 1/sqrt(128)
  float s = 0.f;
  for (int d=0; d<128; d++) s += qv[d]*wk[d*128+i];
  qk[b*128+i] = s*scale;
  if (i==0){
    float c = 0.f;
    for (int d=0; d<128; d++) c += qv[d]*bk[d];
    cbv[b] = c*scale;
  }
}

// ---- fused scores + weighted sum: one pass over x3 ----
__global__ __launch_bounds__(256)
void k_attn(const bf16* __restrict__ x3, const float* __restrict__ qk,
            const float* __restrict__ cbv, float* __restrict__ xa,
            float* __restrict__ sums){
  __shared__ float qks[128];
  __shared__ float red[2048];
  __shared__ float wsm[4];
  int b = blockIdx.x >> 2, seg = blockIdx.x & 3;
  int tid = threadIdx.x;
  int lc = tid & 15, rg = tid >> 4;
  if (tid < 128) qks[tid] = qk[b*128 + tid];
  __syncthreads();
  float cb = cbv[b];
  const char* base = (const char*)x3 + (size_t)b*LL*ROWB;
  const float* qp = qks + lc*8;
  float a[8] = {0,0,0,0,0,0,0,0};
  float esum = 0.f;
  for (int it=0; it<64; it++){
    int l = seg*1024 + it*16 + rg;
    uint4 v = *(const uint4*)(base + l*ROWB + ((lc ^ (l&7))<<4));
    float p = bf2f(v.x)*qp[0] + bf2f(v.x>>16)*qp[1]
            + bf2f(v.y)*qp[2] + bf2f(v.y>>16)*qp[3]
            + bf2f(v.z)*qp[4] + bf2f(v.z>>16)*qp[5]
            + bf2f(v.w)*qp[6] + bf2f(v.w>>16)*qp[7];
    p += __shfl_xor(p, 1); p += __shfl_xor(p, 2);
    p += __shfl_xor(p, 4); p += __shfl_xor(p, 8);
    if (l < LP3){
      float e = __expf(p + cb);
      esum += e;
      acc8(a, v, e);
    }
  }
  #pragma unroll
  for (int j=0;j<8;j++) red[tid*8+j] = a[j];
  esum += __shfl_xor(esum, 16);
  esum += __shfl_xor(esum, 32);
  if ((tid & 63) == 0) wsm[tid>>6] = esum;
  __syncthreads();
  if (tid < 128){
    int lc2 = tid >> 3, j = tid & 7;
    float s = 0.f;
    for (int rg2=0; rg2<16; rg2++) s += red[(rg2*16+lc2)*8 + j];
    atomicAdd(&xa[b*128 + tid], s);
  }
  if (tid == 0) atomicAdd(&sums[b], wsm[0]+wsm[1]+wsm[2]+wsm[3]);
}

// ---- out = Wv.(xa/sum) + bv ----
__global__ void k_out(const float* __restrict__ xa, const float* __restrict__ sums,
                      const float* __restrict__ wv, const float* __restrict__ bv,
                      float* __restrict__ out){
  __shared__ float xs[128];
  int b = blockIdx.x, i = threadIdx.x;
  xs[i] = xa[b*128+i] / sums[b];
  __syncthreads();
  float o = bv[i];
  for (int j=0;j<128;j++) o += wv[i*128+j]*xs[j];
  out[b*128+i] = o;
}

extern "C" void kernel_launch(void* const* d_in, const int* in_sizes, int n_in,
                              void* d_out, int out_size, void* d_ws, size_t ws_size,
                              hipStream_t stream){
  const int*   tokens = (const int*)d_in[0];
  const float* emb    = (const float*)d_in[1];
  const float* w1     = (const float*)d_in[2];
  const float* b1     = (const float*)d_in[3];
  const float* wr     = (const float*)d_in[4];
  const float* br     = (const float*)d_in[5];
  const float* wqw    = (const float*)d_in[6];
  const float* wqb    = (const float*)d_in[7];
  const float* wkw    = (const float*)d_in[8];
  const float* wkb    = (const float*)d_in[9];
  const float* wvw    = (const float*)d_in[10];
  const float* wvb    = (const float*)d_in[11];
  float* out = (float*)d_out;

  const size_t X3SZ  = (size_t)BB*LL*ROWB;           // 134217728
  const size_t WGSZ  = (size_t)(NSTEP+3)*8192;       // 909312 (3 pad steps)
  const size_t AUXSZ = 204800;
  const size_t NEED  = X3SZ + WGSZ + AUXSZ;
  if (ws_size < NEED){
    hipMemsetAsync(d_out, 0, (size_t)out_size*4, stream);
    return;
  }
  char* ws = (char*)d_ws;
  bf16*  x3    = (bf16*)ws;
  bf16*  wg    = (bf16*)(ws + X3SZ);
  char*  aux   = ws + X3SZ + WGSZ;
  float* meanv = (float*)aux;
  float* xabuf = (float*)(aux + 65536);
  float* sums  = (float*)(aux + 131072);
  float* qkbuf = (float*)(aux + 135168);
  float* cbbuf = (float*)(aux + 200704);

  hipMemsetAsync(aux, 0, 135168, stream);            // meanv + xa + sums
  k_prep_w<<<1728, 256, 0, stream>>>(w1, wr, wg);
  k_fused<<<4096, 256, 0, stream>>>(tokens, emb, wg, b1, br, x3, meanv);
  k_qk<<<128, 128, 0, stream>>>(meanv, wqw, wqb, wkw, wkb, qkbuf, cbbuf);
  k_attn<<<512, 256, 0, stream>>>(x3, qkbuf, cbbuf, xabuf, sums);
  k_out<<<128, 128, 0, stream>>>(xabuf, sums, wvw, wvb, out);
}

// Round 5
// 502.674 us; speedup vs baseline: 1.4823x; 1.0522x over previous
//
#include <hip/hip_runtime.h>
#include <hip/hip_bf16.h>
#include <math.h>

#define BB 128
#define LL 4096
#define ROWB 256            // bytes per activation row (128 bf16)
#define LP3 4072            // valid rows after 3 VALID convs
#define TROWS 168           // LDS tile rows (128 out + 24 halo + clamp pad)
#define XB (TROWS*ROWB)     // 43008
#define EOFF XB             // emb table bf16 (1024 B)
#define TOFF (EOFF + 1024)  // tokens (168*4 B)
#define LDSSZ (TOFF + 672)  // 44704 -> 3 blocks/CU
#define REDOFF 33024        // mean-reduction scratch inside X rows 129..161
#define NSTEP 108           // 3 layers x 36 K-steps
#define WELEM (NSTEP*4096)  // real weight elements

typedef __bf16 bf16;
typedef __bf16 bf16x8 __attribute__((ext_vector_type(8)));
typedef float  f32x4  __attribute__((ext_vector_type(4)));

#define MFMA(va,vb,vc) __builtin_amdgcn_mfma_f32_16x16x32_bf16(va,vb,vc,0,0,0)

__device__ __forceinline__ float bf2f(unsigned int u){
  union{unsigned int i; float f;} c; c.i = (u & 0xffffu) << 16; return c.f;
}
__device__ __forceinline__ unsigned short f2bfbits(float f){
  union { bf16 h; unsigned short s; } u; u.h = (bf16)f; return u.s;
}
__device__ __forceinline__ void acc8(float* a, uint4 v, float s){
  a[0] += s*bf2f(v.x); a[1] += s*bf2f(v.x>>16);
  a[2] += s*bf2f(v.y); a[3] += s*bf2f(v.y>>16);
  a[4] += s*bf2f(v.z); a[5] += s*bf2f(v.z>>16);
  a[6] += s*bf2f(v.w); a[7] += s*bf2f(v.w>>16);
}

// ---- weight re-layout. Step s = layer*36 + tap*4 + cb (8 KB each).
// elem = wm*2048 + mf*512 + g*128 + c16*8 + j ; cout = wm*64+mf*16+c16 ; cin = cb*32+g*8+j
// -> per-wave A frag (wm,mf) = 1024 contiguous bytes (lane*16): coalesced global load.
__global__ void k_prep_w(const float* __restrict__ w1, const float* __restrict__ wr,
                         bf16* __restrict__ wg){
  int idx = blockIdx.x*256 + threadIdx.x;
  if (idx >= WELEM) return;
  int s    = idx >> 12;
  int r12  = idx & 4095;
  int wm   = r12 >> 11;
  int mf   = (r12 >> 9) & 3;
  int g    = (r12 >> 7) & 3;
  int c16  = (r12 >> 3) & 15;
  int j    = r12 & 7;
  int layer = s / 36;
  int w36   = s - layer*36;
  int tap = w36 >> 2, cb = w36 & 3;
  int cout = wm*64 + mf*16 + c16;
  int cin  = cb*32 + g*8 + j;
  float w = (layer==0) ? w1[(cout*128+cin)*9 + tap]
                       : wr[(((layer-1)*128 + cout)*128 + cin)*9 + tap];
  wg[idx] = (bf16)w;
}

// A fragments for step tt: 4 coalesced 16B global loads (L1/L2-resident blob)
#define GLOADA(P0,P1,P2,P3,tt) do{                                       \
  const char* p_ = wA + (size_t)(tt)*8192;                               \
  P0 = *(const bf16x8*)(p_);                                             \
  P1 = *(const bf16x8*)(p_+1024);                                        \
  P2 = *(const bf16x8*)(p_+2048);                                        \
  P3 = *(const bf16x8*)(p_+3072);                                        \
}while(0)

// B fragments for K-step kss from swizzled X rows (one vaddr + imm offsets)
#define PRELOADB(B0,B1,B2,B3,B4,kss) do{                                 \
  const int tap_ = (kss)>>2;                                             \
  const int ch_ = ((((((kss)&3)<<2)+g16) ^ ((r16+tap_)&7)) << 4);        \
  const char* bp_ = bBase + tap_*256 + ch_;                              \
  B0 = *(const bf16x8*)(bp_);                                            \
  B1 = *(const bf16x8*)(bp_+4096);                                       \
  B2 = *(const bf16x8*)(bp_+8192);                                       \
  B3 = *(const bf16x8*)(bp_+12288);                                      \
  if (five) B4 = *(const bf16x8*)(bp_+16384);                            \
}while(0)

#define DOMFMA(A0,A1,A2,A3,B0,B1,B2,B3,B4) do{                           \
  __builtin_amdgcn_s_setprio(1);                                         \
  acc[0][0]=MFMA(A0,B0,acc[0][0]); acc[1][0]=MFMA(A1,B0,acc[1][0]);      \
  acc[2][0]=MFMA(A2,B0,acc[2][0]); acc[3][0]=MFMA(A3,B0,acc[3][0]);      \
  acc[0][1]=MFMA(A0,B1,acc[0][1]); acc[1][1]=MFMA(A1,B1,acc[1][1]);      \
  acc[2][1]=MFMA(A2,B1,acc[2][1]); acc[3][1]=MFMA(A3,B1,acc[3][1]);      \
  acc[0][2]=MFMA(A0,B2,acc[0][2]); acc[1][2]=MFMA(A1,B2,acc[1][2]);      \
  acc[2][2]=MFMA(A2,B2,acc[2][2]); acc[3][2]=MFMA(A3,B2,acc[3][2]);      \
  acc[0][3]=MFMA(A0,B3,acc[0][3]); acc[1][3]=MFMA(A1,B3,acc[1][3]);      \
  acc[2][3]=MFMA(A2,B3,acc[2][3]); acc[3][3]=MFMA(A3,B3,acc[3][3]);      \
  if (five){                                                             \
    acc[0][4]=MFMA(A0,B4,acc[0][4]); acc[1][4]=MFMA(A1,B4,acc[1][4]);    \
    acc[2][4]=MFMA(A2,B4,acc[2][4]); acc[3][4]=MFMA(A3,B4,acc[3][4]);    \
  }                                                                      \
  __builtin_amdgcn_s_setprio(0);                                         \
}while(0)

// ---- fused embed + 3 convs + mean partials; barrier-free K-loop ----
// Weights: global->registers (no LDS ring). X: LDS, read-only per layer,
// updated in place at layer epilogue (2 barriers/layer total).
__global__ __launch_bounds__(256, 3)
void k_fused(const int* __restrict__ tokens, const float* __restrict__ emb,
             const bf16* __restrict__ wg, const float* __restrict__ b1,
             const float* __restrict__ br, bf16* __restrict__ x3,
             float* __restrict__ meanv){
  __shared__ __align__(16) char lds[LDSSZ];
  const int tid  = threadIdx.x;
  const int lane = tid & 63;
  const int w    = tid >> 6;
  const int wm   = w >> 1, wn = w & 1;
  const int b    = blockIdx.x >> 5;
  const int l0   = (blockIdx.x & 31) << 7;
  const int g16  = lane >> 4, r16 = lane & 15;
  const char* wbytes = (const char*)wg;
  const char* wA = wbytes + (wm<<12) + (lane<<4);

  int*  Tk = (int*)(lds + TOFF);
  bf16* Eb = (bf16*)(lds + EOFF);
  if (tid < TROWS){
    int l = l0 + tid; if (l > LL-1) l = LL-1;   // clamped halo (rows masked later)
    Tk[tid] = tokens[b*LL + l];
  }
  Eb[tid]     = (bf16)emb[tid];
  Eb[tid+256] = (bf16)emb[tid+256];
  __syncthreads();
  for (int t2 = tid; t2 < TROWS*16; t2 += 256){
    int s = t2 >> 4, c16 = t2 & 15;
    bf16x8 v = *(const bf16x8*)((const char*)Eb + Tk[s]*256 + c16*16);
    *(bf16x8*)(lds + s*ROWB + ((c16 ^ (s&7))<<4)) = v;
  }
  __syncthreads();

  for (int layer = 0; layer < 3; ++layer){
    const int layer36 = layer*36;
    const int rowbase = wn * ((layer==2) ? 64 : 80);
    const bool five = (layer < 2) && (wn == 0);
    const char* bBase = lds + (rowbase + r16)*256;
    f32x4 acc[4][5];
    #pragma unroll
    for (int i=0;i<4;i++)
      #pragma unroll
      for (int j=0;j<5;j++) acc[i][j] = (f32x4){0.f,0.f,0.f,0.f};

    bf16x8 P0,P1,P2,P3,Q0,Q1,Q2,Q3;
    bf16x8 B0,B1,B2,B3,B4,D0,D1,D2,D3,D4;
    GLOADA(P0,P1,P2,P3, layer36);
    GLOADA(Q0,Q1,Q2,Q3, layer36+1);
    PRELOADB(B0,B1,B2,B3,B4, 0);

    #pragma unroll 1
    for (int it = 0; it < 18; ++it){
      const int ks = it << 1;
      const int t  = layer36 + ks;
      PRELOADB(D0,D1,D2,D3,D4, ks+1);
      DOMFMA(P0,P1,P2,P3, B0,B1,B2,B3,B4);
      GLOADA(P0,P1,P2,P3, t+2);            // WAR on P keeps this after MFMA
      if (ks < 34) PRELOADB(B0,B1,B2,B3,B4, ks+2);
      DOMFMA(Q0,Q1,Q2,Q3, D0,D1,D2,D3,D4);
      GLOADA(Q0,Q1,Q2,Q3, t+3);            // blob padded +3 steps: always valid
    }
    __syncthreads();                        // all reads of X(layer) done

    // epilogue: +bias, pack bf16, write in place
    const float* bias = (layer == 0) ? b1 : (br + (layer-1)*128);
    const int nfmax = five ? 5 : 4;
    #pragma unroll
    for (int mf=0; mf<4; mf++){
      int mb = wm*64 + mf*16 + (g16<<2);
      float4 bvx = *(const float4*)(bias + mb);
      #pragma unroll
      for (int nf=0; nf<5; nf++){
        if (nf < nfmax){
          int nn = rowbase + nf*16 + r16;
          f32x4 v = acc[mf][nf];
          ushort4 pk;
          pk.x = f2bfbits(v[0] + bvx.x);
          pk.y = f2bfbits(v[1] + bvx.y);
          pk.z = f2bfbits(v[2] + bvx.z);
          pk.w = f2bfbits(v[3] + bvx.w);
          int chunk = (mb>>3) ^ (nn&7);
          *(ushort4*)(lds + nn*ROWB + (chunk<<4) + ((mb&7)<<1)) = pk;
        }
      }
    }
    __syncthreads();                        // writes visible before next layer
  }

  // store rows 0..127 (swizzled image identical in LDS and global)
  char* dst = (char*)x3 + ((size_t)b*LL + l0)*ROWB;
  #pragma unroll
  for (int p=0;p<8;p++){
    int off = p*4096 + tid*16;
    int row = off >> 8;
    if (l0 + row < LP3)
      *(uint4*)(dst + off) = *(const uint4*)(lds + off);
  }
  // mean partials: column sums of this tile -> atomicAdd (meanv pre-zeroed)
  {
    int lc = tid & 15, rg = tid >> 4;
    float am[8] = {0,0,0,0,0,0,0,0};
    for (int l = rg; l < 128; l += 16){
      if (l0 + l < LP3){
        uint4 v = *(const uint4*)(lds + l*ROWB + ((lc ^ (l&7))<<4));
        acc8(am, v, 1.0f);
      }
    }
    float* red = (float*)(lds + REDOFF);    // rows 129..161: not read below
    __syncthreads();
    #pragma unroll
    for (int j=0;j<8;j++) red[tid*8+j] = am[j];
    __syncthreads();
    if (tid < 128){
      int lc2 = tid >> 3, j = tid & 7;
      float s = 0.f;
      for (int rg2=0; rg2<16; rg2++) s += red[(rg2*16+lc2)*8 + j];
      atomicAdd(&meanv[b*128 + tid], s);
    }
  }
}

// ---- q = Wq.(mean) + bq ; qk = Wk^T q (scaled) ; cb = q.bk (scaled) ----
__global__ void k_qk(const float* __restrict__ meanv, const float* __restrict__ wq,
                     const float* __restrict__ bq, const float* __restrict__ wk,
                     const float* __restrict__ bk, float* __restrict__ qk,
                     float* __restrict__ cbv){
  __shared__ float mv[128], qv[128];
  int b = blockIdx.x, i = threadIdx.x;
  mv[i] = meanv[b*128+i] * (1.0f/LP3);
  __syncthreads();
  float q = bq[i];
  for (int j=0;j<128;j++) q += wq[i*128+j]*mv[j];
  qv[i] = q;
  __syncthreads();
  const float scale = 0.088388347648318447f; // 1/sqrt(128)
  float s = 0.f;
  for (int d=0; d<128; d++) s += qv[d]*wk[d*128+i];
  qk[b*128+i] = s*scale;
  if (i==0){
    float c = 0.f;
    for (int d=0; d<128; d++) c += qv[d]*bk[d];
    cbv[b] = c*scale;
  }
}

// ---- fused scores + weighted sum: one pass over x3 ----
__global__ __launch_bounds__(256)
void k_attn(const bf16* __restrict__ x3, const float* __restrict__ qk,
            const float* __restrict__ cbv, float* __restrict__ xa,
            float* __restrict__ sums){
  __shared__ float qks[128];
  __shared__ float red[2048];
  __shared__ float wsm[4];
  int b = blockIdx.x >> 2, seg = blockIdx.x & 3;
  int tid = threadIdx.x;
  int lc = tid & 15, rg = tid >> 4;
  if (tid < 128) qks[tid] = qk[b*128 + tid];
  __syncthreads();
  float cb = cbv[b];
  const char* base = (const char*)x3 + (size_t)b*LL*ROWB;
  const float* qp = qks + lc*8;
  float a[8] = {0,0,0,0,0,0,0,0};
  float esum = 0.f;
  for (int it=0; it<64; it++){
    int l = seg*1024 + it*16 + rg;
    uint4 v = *(const uint4*)(base + l*ROWB + ((lc ^ (l&7))<<4));
    float p = bf2f(v.x)*qp[0] + bf2f(v.x>>16)*qp[1]
            + bf2f(v.y)*qp[2] + bf2f(v.y>>16)*qp[3]
            + bf2f(v.z)*qp[4] + bf2f(v.z>>16)*qp[5]
            + bf2f(v.w)*qp[6] + bf2f(v.w>>16)*qp[7];
    p += __shfl_xor(p, 1); p += __shfl_xor(p, 2);
    p += __shfl_xor(p, 4); p += __shfl_xor(p, 8);
    if (l < LP3){
      float e = __expf(p + cb);
      esum += e;
      acc8(a, v, e);
    }
  }
  #pragma unroll
  for (int j=0;j<8;j++) red[tid*8+j] = a[j];
  esum += __shfl_xor(esum, 16);
  esum += __shfl_xor(esum, 32);
  if ((tid & 63) == 0) wsm[tid>>6] = esum;
  __syncthreads();
  if (tid < 128){
    int lc2 = tid >> 3, j = tid & 7;
    float s = 0.f;
    for (int rg2=0; rg2<16; rg2++) s += red[(rg2*16+lc2)*8 + j];
    atomicAdd(&xa[b*128 + tid], s);
  }
  if (tid == 0) atomicAdd(&sums[b], wsm[0]+wsm[1]+wsm[2]+wsm[3]);
}

// ---- out = Wv.(xa/sum) + bv ----
__global__ void k_out(const float* __restrict__ xa, const float* __restrict__ sums,
                      const float* __restrict__ wv, const float* __restrict__ bv,
                      float* __restrict__ out){
  __shared__ float xs[128];
  int b = blockIdx.x, i = threadIdx.x;
  xs[i] = xa[b*128+i] / sums[b];
  __syncthreads();
  float o = bv[i];
  for (int j=0;j<128;j++) o += wv[i*128+j]*xs[j];
  out[b*128+i] = o;
}

extern "C" void kernel_launch(void* const* d_in, const int* in_sizes, int n_in,
                              void* d_out, int out_size, void* d_ws, size_t ws_size,
                              hipStream_t stream){
  const int*   tokens = (const int*)d_in[0];
  const float* emb    = (const float*)d_in[1];
  const float* w1     = (const float*)d_in[2];
  const float* b1     = (const float*)d_in[3];
  const float* wr     = (const float*)d_in[4];
  const float* br     = (const float*)d_in[5];
  const float* wqw    = (const float*)d_in[6];
  const float* wqb    = (const float*)d_in[7];
  const float* wkw    = (const float*)d_in[8];
  const float* wkb    = (const float*)d_in[9];
  const float* wvw    = (const float*)d_in[10];
  const float* wvb    = (const float*)d_in[11];
  float* out = (float*)d_out;

  const size_t X3SZ  = (size_t)BB*LL*ROWB;           // 134217728
  const size_t WGSZ  = (size_t)(NSTEP+3)*8192;       // 909312 (3 pad steps)
  const size_t AUXSZ = 204800;
  const size_t NEED  = X3SZ + WGSZ + AUXSZ;
  if (ws_size < NEED){
    hipMemsetAsync(d_out, 0, (size_t)out_size*4, stream);
    return;
  }
  char* ws = (char*)d_ws;
  bf16*  x3    = (bf16*)ws;
  bf16*  wg    = (bf16*)(ws + X3SZ);
  char*  aux   = ws + X3SZ + WGSZ;
  float* meanv = (float*)aux;
  float* xabuf = (float*)(aux + 65536);
  float* sums  = (float*)(aux + 131072);
  float* qkbuf = (float*)(aux + 135168);
  float* cbbuf = (float*)(aux + 200704);

  hipMemsetAsync(aux, 0, 135168, stream);            // meanv + xa + sums
  k_prep_w<<<1728, 256, 0, stream>>>(w1, wr, wg);
  k_fused<<<4096, 256, 0, stream>>>(tokens, emb, wg, b1, br, x3, meanv);
  k_qk<<<128, 128, 0, stream>>>(meanv, wqw, wqb, wkw, wkb, qkbuf, cbbuf);
  k_attn<<<512, 256, 0, stream>>>(x3, qkbuf, cbbuf, xabuf, sums);
  k_out<<<128, 128, 0, stream>>>(xabuf, sums, wvw, wvb, out);
}